// Round 12
// baseline (671.039 us; speedup 1.0000x reference)
//
#include <hip/hip_runtime.h>

#define BB 8
#define TT 2048
#define DD 64
#define HH 1024
#define OO 16
#define NGRP 16
#define GBLK 16
#define KCH 32
#define CHUNK 64
#define WASH 48
#define STEPS (CHUNK + WASH)   // 112
#define ZPS 36                 // zp stride: 2-way banks (free) on write + finalize read

typedef __attribute__((ext_vector_type(8))) short short8;
typedef __attribute__((ext_vector_type(4))) float f32x4;

// ws layout (f32 units)
// flags: [grp][pblk][pwave][cblk] u32, 128B apart = 1,048,576 u32 (4 MB)
#define WS_HX   1048576                 // h: [NGRP][2][KCH][HH] bf16 = 2 MB
#define WS_UHI  (WS_HX + 524288)        // [BB][TT][DD] bf16 = 2 MB
#define WS_PART (WS_UHI + 524288)       // [NGRP][GBLK][TT][OO] f32

#define FLAG_IDX(g, pb, pw, cb) (((((g)*GBLK + (pb)) * 8 + (pw)) * GBLK + (cb)) * 32)

__device__ __forceinline__ unsigned short f2bf(float x) {
  union { float f; unsigned u; } v; v.f = x;
  unsigned r = v.u + 0x7FFF + ((v.u >> 16) & 1);   // RNE
  return (unsigned short)(r >> 16);
}
__device__ __forceinline__ float bf2f(unsigned short h) {
  union { unsigned u; float f; } v; v.u = ((unsigned)h) << 16; return v.f;
}

// device-coherent ops (served at the coherence point; proven protocol)
__device__ __forceinline__ uint4 ld_cohx4(const void* p) {
  uint4 r;
  asm volatile("global_load_dwordx4 %0, %1, off sc0 sc1" : "=&v"(r) : "v"(p));
  return r;
}
__device__ __forceinline__ void st_coh(unsigned* p, unsigned v) {
  asm volatile("global_store_dword %0, %1, off sc0 sc1" :: "v"(p), "v"(v) : "memory");
}
__device__ __forceinline__ unsigned ld_flag(const unsigned* p) {
  unsigned r;
  asm volatile("global_load_dword %0, %1, off sc0 sc1\n\ts_waitcnt vmcnt(0)"
               : "=&v"(r) : "v"(p) : "memory");
  return r;
}

__global__ __launch_bounds__(256) void ucvt_kernel(const float* __restrict__ u,
    unsigned short* __restrict__ uhi) {
  int i = blockIdx.x * 256 + threadIdx.x;
  float4 v = ((const float4*)u)[i];
  ushort4 h;
  h.x = f2bf(v.x); h.y = f2bf(v.y); h.z = f2bf(v.z); h.w = f2bf(v.w);
  ((ushort4*)uhi)[i] = h;
}

__global__ __launch_bounds__(512, 1) void esn_kernel(
    const float* __restrict__ w, const float* __restrict__ w_in,
    const float* __restrict__ w_bias, const float* __restrict__ w_out,
    float* __restrict__ ws)
{
  __shared__ float zp_sh[8 * 64 * ZPS];  // [wave][row*ZPS + ch]  (72 KB)
  __shared__ float hn_sh[64 * 33];       // [row*33 + ch]
  __shared__ float wout_sh[64 * 17];     // [row*17 + o]

  const int tid = threadIdx.x;
  const int lane = tid & 63;
  const int rg = tid >> 6;            // wave 0..7, owns k-slice [rg*128, rg*128+128)
  const int lm = lane & 15;
  const int l4 = lane >> 4;
  const int bid = blockIdx.x;
  const int grp = bid & 15;           // group = dir*8 + b
  const int blk = bid >> 4;           // owns rows [blk*64, blk*64+64)
  const int dir = grp >> 3;
  const int b = grp & 7;
  const int row0 = blk * 64;

  unsigned* flags = (unsigned*)ws;
  unsigned short* hx = (unsigned short*)(ws + WS_HX);
  const unsigned short* uhi = (const unsigned short*)(ws + WS_UHI);
  float* partial = ws + WS_PART;

  // ---- A fragments (split bf16): rows row0+mt*16+lm, k=(rg*4+kt)*32+l4*8+j
  short8 Ahi[4][4], Alo[4][4];
#pragma unroll
  for (int mt = 0; mt < 4; ++mt) {
#pragma unroll
    for (int kt = 0; kt < 4; ++kt) {
      const int row = row0 + mt * 16 + lm;
      const int kb = (rg * 4 + kt) * 32 + l4 * 8;
      const float* wp = w + (size_t)row * HH + kb;
      short8 h8, l8;
#pragma unroll
      for (int i2 = 0; i2 < 2; ++i2) {
        float4 v = ((const float4*)wp)[i2];
        float xs[4] = {v.x, v.y, v.z, v.w};
#pragma unroll
        for (int j = 0; j < 4; ++j) {
          unsigned short hb = f2bf(xs[j]);
          h8[i2 * 4 + j] = (short)hb;
          l8[i2 * 4 + j] = (short)f2bf(xs[j] - bf2f(hb));
        }
      }
      Ahi[mt][kt] = h8; Alo[mt][kt] = l8;
    }
  }
  // u projection A-fragments (hi only): waves 0,1 own K=64 as 2 k-tiles
  short8 UAhi[4];
  if (rg < 2) {
#pragma unroll
    for (int mt = 0; mt < 4; ++mt) {
      const int row = row0 + mt * 16 + lm;
      const int kb = rg * 32 + l4 * 8;
      const float* wp = w_in + (size_t)row * DD + kb;
      short8 h8;
#pragma unroll
      for (int i2 = 0; i2 < 2; ++i2) {
        float4 v = ((const float4*)wp)[i2];
        float xs[4] = {v.x, v.y, v.z, v.w};
#pragma unroll
        for (int j = 0; j < 4; ++j) h8[i2 * 4 + j] = (short)f2bf(xs[j]);
      }
      UAhi[mt] = h8;
    }
  }

  for (int idx = tid; idx < 1024; idx += 512) {
    int r = idx >> 4, o = idx & 15;
    wout_sh[r * 17 + o] = w_out[(size_t)(1 + dir * HH + row0 + r) * OO + o];
  }

  // finalize mapping: thread -> chains ch, ch+16; rows 2q2, 2q2+1
  const int ch = tid & 15;
  const int q2 = tid >> 4;            // 0..31
  const float bias0 = w_bias[row0 + 2 * q2];
  const float bias1 = w_bias[row0 + 2 * q2 + 1];
  float hp0 = 0.f, hp1 = 0.f, hp2 = 0.f, hp3 = 0.f;
  __syncthreads();

#pragma unroll 1
  for (int i = 0; i < STEPS; ++i) {
    const int par = i & 1;
    const unsigned short* hxbuf = hx + (size_t)(grp * 2 + par) * (KCH * HH);

    // ---- u fragments (independent of h; latency overlaps the poll)
    uint4 ub4[2];
    if (rg < 2) {
#pragma unroll
      for (int nt = 0; nt < 2; ++nt) {
        int cc = nt * 16 + lm;
        int ts = cc * CHUNK - WASH; if (ts < 0) ts = 0;
        int tau = ts + i;
        int t = dir ? (TT - 1 - tau) : tau;
        ub4[nt] = *(const uint4*)(uhi + ((size_t)(b * TT + t)) * DD + rg * 32 + l4 * 8);
      }
    }

    // ---- poll: 16 producer-wave flags (2 blocks x 8 waves), own replica lines
    if (i > 0) {
      const unsigned tg = (unsigned)i;
      unsigned v;
      do {
        v = 0xFFFFFFFFu;
        if (lane < 16)
          v = ld_flag(flags + FLAG_IDX(grp, 2 * rg + (lane >> 3), lane & 7, blk));
      } while (!__all(v >= tg));
      asm volatile("" ::: "memory");
    }

    // ---- B loads: own k-slice for both chain-halves (8 coherent dwordx4)
    uint4 Bv0[4], Bv1[4];
#pragma unroll
    for (int kt = 0; kt < 4; ++kt) {
      const int ko = (rg * 4 + kt) * 32 + l4 * 8;
      Bv0[kt] = ld_cohx4(hxbuf + (size_t)lm * HH + ko);
      Bv1[kt] = ld_cohx4(hxbuf + (size_t)(16 + lm) * HH + ko);
    }
    asm volatile("s_waitcnt vmcnt(0)" ::: "memory");
    __builtin_amdgcn_sched_barrier(0);

    f32x4 acc0[4], acc1[4];
#pragma unroll
    for (int mt = 0; mt < 4; ++mt) {
      acc0[mt] = (f32x4){0.f, 0.f, 0.f, 0.f};
      acc1[mt] = (f32x4){0.f, 0.f, 0.f, 0.f};
    }
#pragma unroll
    for (int kt = 0; kt < 4; ++kt) {
      short8 b0 = *(short8*)&Bv0[kt];
      short8 b1 = *(short8*)&Bv1[kt];
#pragma unroll
      for (int mt = 0; mt < 4; ++mt) {
        acc0[mt] = __builtin_amdgcn_mfma_f32_16x16x32_bf16(Ahi[mt][kt], b0, acc0[mt], 0, 0, 0);
        acc0[mt] = __builtin_amdgcn_mfma_f32_16x16x32_bf16(Alo[mt][kt], b0, acc0[mt], 0, 0, 0);
        acc1[mt] = __builtin_amdgcn_mfma_f32_16x16x32_bf16(Ahi[mt][kt], b1, acc1[mt], 0, 0, 0);
        acc1[mt] = __builtin_amdgcn_mfma_f32_16x16x32_bf16(Alo[mt][kt], b1, acc1[mt], 0, 0, 0);
      }
    }
    if (rg < 2) {
      short8 u0 = *(short8*)&ub4[0];
      short8 u1 = *(short8*)&ub4[1];
#pragma unroll
      for (int mt = 0; mt < 4; ++mt) {
        acc0[mt] = __builtin_amdgcn_mfma_f32_16x16x32_bf16(UAhi[mt], u0, acc0[mt], 0, 0, 0);
        acc1[mt] = __builtin_amdgcn_mfma_f32_16x16x32_bf16(UAhi[mt], u1, acc1[mt], 0, 0, 0);
      }
    }

    // ---- per-wave K-partials to LDS (2-way banks: free)
#pragma unroll
    for (int mt = 0; mt < 4; ++mt)
#pragma unroll
      for (int j = 0; j < 4; ++j) {
        zp_sh[rg * (64 * ZPS) + (mt * 16 + l4 * 4 + j) * ZPS + lm] = acc0[mt][j];
        zp_sh[rg * (64 * ZPS) + (mt * 16 + l4 * 4 + j) * ZPS + 16 + lm] = acc1[mt][j];
      }
    __syncthreads();

    // ---- finalize 4 states: (rows 2q2,2q2+1) x (chains ch, ch+16)
    float z0 = bias0, z1 = bias1, z2 = bias0, z3 = bias1;
#pragma unroll
    for (int g2 = 0; g2 < 8; ++g2) {
      const float* zb = zp_sh + g2 * (64 * ZPS);
      z0 += zb[(2 * q2) * ZPS + ch];
      z1 += zb[(2 * q2 + 1) * ZPS + ch];
      z2 += zb[(2 * q2) * ZPS + 16 + ch];
      z3 += zb[(2 * q2 + 1) * ZPS + 16 + ch];
    }
    float e0 = __expf(2.f * z0), e1 = __expf(2.f * z1);
    float e2 = __expf(2.f * z2), e3 = __expf(2.f * z3);
    hp0 = 0.1f * hp0 + 0.9f * (1.f - 2.f * __builtin_amdgcn_rcpf(e0 + 1.f));
    hp1 = 0.1f * hp1 + 0.9f * (1.f - 2.f * __builtin_amdgcn_rcpf(e1 + 1.f));
    hp2 = 0.1f * hp2 + 0.9f * (1.f - 2.f * __builtin_amdgcn_rcpf(e2 + 1.f));
    hp3 = 0.1f * hp3 + 0.9f * (1.f - 2.f * __builtin_amdgcn_rcpf(e3 + 1.f));
    hn_sh[(2 * q2) * 33 + ch] = hp0;
    hn_sh[(2 * q2 + 1) * 33 + ch] = hp1;
    hn_sh[(2 * q2) * 33 + 16 + ch] = hp2;
    hn_sh[(2 * q2 + 1) * 33 + 16 + ch] = hp3;
    // publish bf16 h: row-pairs packed; per-wave flag after own stores ack
    unsigned short* hw = hx + (size_t)(grp * 2 + (par ^ 1)) * (KCH * HH);
    unsigned pv0 = (unsigned)f2bf(hp0) | ((unsigned)f2bf(hp1) << 16);
    unsigned pv1 = (unsigned)f2bf(hp2) | ((unsigned)f2bf(hp3) << 16);
    st_coh((unsigned*)(hw + (size_t)ch * HH + row0 + 2 * q2), pv0);
    st_coh((unsigned*)(hw + (size_t)(16 + ch) * HH + row0 + 2 * q2), pv1);
    asm volatile("s_waitcnt vmcnt(0)" ::: "memory");   // this wave's h at L3
    if (lane < 16)
      st_coh(flags + FLAG_IDX(grp, blk, rg, lane), (unsigned)(i + 1));
    __syncthreads();   // hn_sh complete for readout

    // ---- readout partials: 4 chains per wave
#pragma unroll
    for (int cidx = 0; cidx < 4; ++cidx) {
      int cc = rg * 4 + cidx;
      int ts = cc * CHUNK - WASH; if (ts < 0) ts = 0;
      int tau = ts + i;
      int rel = tau - cc * CHUNK;
      if (rel >= 0 && rel < CHUNK) {
        int t_out = dir ? (TT - 1 - tau) : tau;
        float s = 0.f;
#pragma unroll
        for (int j = 0; j < 16; ++j)
          s += hn_sh[(l4 * 16 + j) * 33 + cc] * wout_sh[(l4 * 16 + j) * 17 + lm];
        s += __shfl_xor(s, 16);
        s += __shfl_xor(s, 32);
        if (lane < 16)
          partial[((size_t)(grp * GBLK + blk) * TT + t_out) * OO + lm] = s;
      }
    }
  }
}

__global__ __launch_bounds__(256) void combine_kernel(
    const float* __restrict__ w_out, const float* __restrict__ partial,
    float* __restrict__ out)
{
  int idx = blockIdx.x * 256 + threadIdx.x;   // (b*2048+t)*16+o
  int o = idx & 15;
  int bt = idx >> 4;
  int b_ = bt >> 11;
  int t_ = bt & 2047;
  float s = w_out[o];   // bias row
#pragma unroll 1
  for (int dir = 0; dir < 2; ++dir)
#pragma unroll
    for (int g = 0; g < 16; ++g)
      s += partial[((size_t)((dir * 8 + b_) * 16 + g) * TT + t_) * OO + o];
  out[idx] = s;
}

extern "C" void kernel_launch(void* const* d_in, const int* in_sizes, int n_in,
                              void* d_out, int out_size, void* d_ws, size_t ws_size,
                              hipStream_t stream) {
  (void)in_sizes; (void)n_in; (void)out_size; (void)ws_size;
  const float* u      = (const float*)d_in[0];
  const float* w      = (const float*)d_in[1];
  const float* w_in   = (const float*)d_in[2];
  const float* w_bias = (const float*)d_in[3];
  const float* w_out  = (const float*)d_in[4];
  float* out = (float*)d_out;
  float* ws  = (float*)d_ws;

  // zero flags + bf16 h double buffers each replay
  (void)hipMemsetAsync(d_ws, 0, (size_t)(WS_HX + 524288) * 4, stream);

  ucvt_kernel<<<dim3(1024), dim3(256), 0, stream>>>(
      u, (unsigned short*)(ws + WS_UHI));
  esn_kernel<<<dim3(NGRP * GBLK), dim3(512), 0, stream>>>(w, w_in, w_bias, w_out, ws);
  combine_kernel<<<dim3((BB * TT * OO) / 256), dim3(256), 0, stream>>>(
      w_out, ws + WS_PART, out);
}